// Round 20
// baseline (31.940 us; speedup 1.0000x reference)
//
#include <hip/hip_runtime.h>
#include <math.h>

// st_VQEmbedding via LDS-staged MFMA GEMM.
// R20 = R19 + K-split x2: 512-thread blocks (8 waves), PPB=256.
//   waves 0-3 scan codes [0,256), waves 4-7 scan [256,512);
//   each wave owns 4 point-tiles (64 points) -> A-reads per (point x code)
//   halve vs R19 (the now-dominant LDS pipe). 1 block/CU (108KB LDS),
//   8 waves = 2 waves/SIMD (same TLP as R19). amdgpu_waves_per_eu(2,2)
//   pins the register budget at 256 (no 64-VGPR squeeze / spills).
// dist = (x2 - 2*dot) + e2, dot via bf16 2-term split MFMA (al*bh + ah*bl +
// ah*bh, fp32 accum) -- bit-identical chains/term order/tie-break to
// R5/R7/R8/R12/R13/R18/R19 (all passed absmax 0.0).

constexpr int K      = 512;
constexpr int D      = 64;
constexpr int NPTS   = 16 * 4096;    // 65536
constexpr int BLOCK  = 512;          // 8 waves
constexpr int PPB    = 256;          // points per block
constexpr int CHUNK  = 32;           // codes per chunk (per half)
constexpr int NCH    = 8;            // chunks per half (8 x 32 = 256 codes)
constexpr int GPC    = CHUNK * 8;    // 256 16B-granules per chunk per array
constexpr int ZSTR   = 17;           // z-tile row stride in float4 (272 B)

typedef __attribute__((ext_vector_type(8))) short  short8;
typedef __attribute__((ext_vector_type(4))) float  f32x4;

#define AS_G (const __attribute__((address_space(1))) void*)
#define AS_L (__attribute__((address_space(3))) void*)

__device__ inline unsigned short bf16_rne(float f) {
    unsigned u = __builtin_bit_cast(unsigned, f);
    u += 0x7fffu + ((u >> 16) & 1u);
    return (unsigned short)(u >> 16);
}
__device__ inline float bf16_f32(unsigned short h) {
    unsigned u = (unsigned)h << 16;
    return __builtin_bit_cast(float, u);
}

// ---- prep: e2 (exact chain) + bf16 hi/lo split, written pre-swizzled ------
// thread t: code k = t>>3, d-slot s = t&7.
// ws granule index = (k>>5)*GPC + (k&31)*8 + (s ^ (k&7))  [GPC=256 relabel]
__global__ void prep_emb(const float* __restrict__ emb,
                         float* __restrict__ e2,
                         short8* __restrict__ wsHi,
                         short8* __restrict__ wsLo)
{
    const int gid = blockIdx.x * 256 + threadIdx.x;   // 0..4095
    const int k = gid >> 3;
    const int s = gid & 7;

    const float4* row = reinterpret_cast<const float4*>(emb + k * D);
    float v[64];
    #pragma unroll
    for (int i = 0; i < 16; ++i) {
        float4 q = row[i];
        v[4*i+0] = q.x; v[4*i+1] = q.y; v[4*i+2] = q.z; v[4*i+3] = q.w;
    }
    if (s == 0) {   // exact sequential unfused e2 (same chain as R1-R19)
        float acc = 0.0f;
        {
            #pragma clang fp contract(off)
            #pragma unroll
            for (int d = 0; d < 64; ++d) acc = acc + v[d] * v[d];
        }
        e2[k] = acc;
    }
    short8 hi, lo;
    #pragma unroll
    for (int e = 0; e < 8; ++e) {
        const float f = v[s * 8 + e];
        const unsigned short h = bf16_rne(f);
        const float r = f - bf16_f32(h);          // exact (Sterbenz)
        hi[e] = (short)h;
        lo[e] = (short)bf16_rne(r);
    }
    const int slot = (k >> 5) * GPC + (k & 31) * 8 + (s ^ (k & 7));
    wsHi[slot] = hi;
    wsLo[slot] = lo;
}

// ---- main: LDS-staged MFMA argmin + gather ---------------------------------
__global__ __launch_bounds__(BLOCK)
__attribute__((amdgpu_waves_per_eu(2, 2)))
void vq_mfma(const float* __restrict__ z,
             const float* __restrict__ emb,
             const float* __restrict__ e2,
             const short8* __restrict__ wsHi,
             const short8* __restrict__ wsLo,
             float* __restrict__ out)
{
    __shared__ short8 Ahi[2][2][GPC];    // [buf][half][granule] 16 KiB
    __shared__ short8 Alo[2][2][GPC];    // 16 KiB
    __shared__ float4 e2L[K / 4];        // 2 KiB
    __shared__ float4 zt[PPB * ZSTR];    // 69.6 KiB padded z-tile
    __shared__ float  bestH[2][PPB];     // 2 KiB
    __shared__ int    bidxH[2][PPB];     // 2 KiB
    __shared__ int    bfin[PPB];         // 1 KiB

    const int tid = threadIdx.x;
    const int w   = tid >> 6;         // wave 0..7
    const int l   = tid & 63;
    const int col = l & 15;           // point within tile / code within tile
    const int kg  = l >> 4;           // k-group / code-row group
    const int h   = w >> 2;           // K-half 0/1
    const int pg  = w & 3;            // point-group (64 points)

    const float4* zf4 = reinterpret_cast<const float4*>(z);
    const float4* ef4 = reinterpret_cast<const float4*>(emb);
    float4*       of4 = reinterpret_cast<float4*>(out);

    const int base = blockIdx.x * PPB;

    // stage chunk-pair i: half0 global chunk i, half1 global chunk 8+i.
    // Each thread stages 1 hi + 1 lo granule (pure linear copy; source is
    // already in LDS-image swizzled order).
    auto stage = [&](int i, int b) {
        const int hf = tid >> 8;             // which half this thread feeds
        const int g  = tid & 255;            // granule within chunk
        const int gc = (hf == 0) ? i : (8 + i);
        const int src = gc * GPC + g;
        __builtin_amdgcn_global_load_lds(AS_G(wsHi + src),
                                         AS_L(&Ahi[b][hf][g]), 16, 0, 0);
        __builtin_amdgcn_global_load_lds(AS_G(wsLo + src),
                                         AS_L(&Alo[b][hf][g]), 16, 0, 0);
    };

    stage(0, 0);   // in flight during z-tile staging
    if (tid < K / 4)   // e2 -> LDS, lane-linear 16B granules
        __builtin_amdgcn_global_load_lds(AS_G(e2 + tid * 4),
                                         AS_L(&e2L[tid]), 16, 0, 0);

    // ---- z-tile: COALESCED global loads -> padded LDS rows (R18 win) ----
    #pragma unroll
    for (int i = 0; i < (PPB * 16) / BLOCK; ++i) {   // 8 iters
        const int idx = i * BLOCK + tid;             // 0..4095
        const float4 v = zf4[base * 16 + idx];
        zt[(idx >> 4) * ZSTR + (idx & 15)] = v;
    }

    __syncthreads();   // z-tile + chunk-pair 0 + e2L resident

    // ---- x2: one point per lane (64 points of this wave's group) ----
    float x2c = 0.0f;
    {
        #pragma clang fp contract(off)
        #pragma unroll
        for (int i = 0; i < 16; ++i) {
            float4 q = zt[(pg * 64 + l) * ZSTR + i];
            x2c = x2c + q.x * q.x;
            x2c = x2c + q.y * q.y;
            x2c = x2c + q.z * q.z;
            x2c = x2c + q.w * q.w;
        }
    }
    float x2v[4];
    #pragma unroll
    for (int p = 0; p < 4; ++p) x2v[p] = __shfl(x2c, p * 16 + col);

    // ---- B-frags for the wave's 4 point-tiles (identical build chain) ----
    short8 bh[4][2], bl[4][2];
    #pragma unroll
    for (int p = 0; p < 4; ++p) {
        const int zrow = (pg * 64 + p * 16 + col) * ZSTR;
        #pragma unroll
        for (int kt = 0; kt < 2; ++kt) {
            const float4 va = zt[zrow + kt * 8 + kg * 2];
            const float4 vb = zt[zrow + kt * 8 + kg * 2 + 1];
            const float xs[8] = {va.x, va.y, va.z, va.w, vb.x, vb.y, vb.z, vb.w};
            #pragma unroll
            for (int e = 0; e < 8; ++e) {
                const unsigned short hh = bf16_rne(xs[e]);
                const float r = xs[e] - bf16_f32(hh);   // exact
                bh[p][kt][e] = (short)hh;
                bl[p][kt][e] = (short)bf16_rne(r);
            }
        }
    }

    // per-point running argmin (wave visit order is ascending k within its
    // half, so strict < preserves first-index semantics).
    float best[4];
    int   bidx[4];
    #pragma unroll
    for (int p = 0; p < 4; ++p) { best[p] = INFINITY; bidx[p] = 0; }

    for (int i = 0; i < NCH; ++i) {
        const int b = i & 1;
        if (i + 1 < NCH) stage(i + 1, b ^ 1);

        #pragma unroll
        for (int t = 0; t < 2; ++t) {
            // swizzled A slots: code_local = t*16+col, sidx = (kt*4+kg)^(col&7)
            const int slot0 = ((t * 16 + col) << 3) | (kg ^ (col & 7)); // kt=0
            const short8 ah0 = Ahi[b][h][slot0];
            const short8 ah1 = Ahi[b][h][slot0 ^ 4];                     // kt=1
            const short8 al0 = Alo[b][h][slot0];
            const short8 al1 = Alo[b][h][slot0 ^ 4];

            const int   kbase = (h * 8 + i) * 32 + t * 16 + kg * 4;
            const float4 e2v  = e2L[kbase >> 2];   // broadcast ds_read

            #pragma unroll
            for (int p = 0; p < 4; ++p) {
                f32x4 acc = {0.f, 0.f, 0.f, 0.f};
                // same term order: per kt {al*bh, ah*bl, ah*bh}
                acc = __builtin_amdgcn_mfma_f32_16x16x32_bf16(al0, bh[p][0], acc, 0, 0, 0);
                acc = __builtin_amdgcn_mfma_f32_16x16x32_bf16(ah0, bl[p][0], acc, 0, 0, 0);
                acc = __builtin_amdgcn_mfma_f32_16x16x32_bf16(ah0, bh[p][0], acc, 0, 0, 0);
                acc = __builtin_amdgcn_mfma_f32_16x16x32_bf16(al1, bh[p][1], acc, 0, 0, 0);
                acc = __builtin_amdgcn_mfma_f32_16x16x32_bf16(ah1, bl[p][1], acc, 0, 0, 0);
                acc = __builtin_amdgcn_mfma_f32_16x16x32_bf16(ah1, bh[p][1], acc, 0, 0, 0);

                const float d0 = (x2v[p] - 2.0f * acc[0]) + e2v.x;
                const float d1 = (x2v[p] - 2.0f * acc[1]) + e2v.y;
                const float d2 = (x2v[p] - 2.0f * acc[2]) + e2v.z;
                const float d3 = (x2v[p] - 2.0f * acc[3]) + e2v.w;

                // tree argmin (ties -> lower k), then strict-< running update
                float mv01 = d0; int mi01 = kbase + 0;
                if (d1 < mv01) { mv01 = d1; mi01 = kbase + 1; }
                float mv23 = d2; int mi23 = kbase + 2;
                if (d3 < mv23) { mv23 = d3; mi23 = kbase + 3; }
                float mv = mv01; int mi = mi01;
                if (mv23 < mv) { mv = mv23; mi = mi23; }
                if (mv < best[p]) { best[p] = mv; bidx[p] = mi; }
            }
        }
        __syncthreads();   // drains stage vmcnt + all waves done with buf b
    }

    // combine 4 kg-groups within the wave: lexicographic (dist, idx)
    #pragma unroll
    for (int p = 0; p < 4; ++p) {
        #pragma unroll
        for (int off = 16; off < 64; off <<= 1) {
            const float ov = __shfl_xor(best[p], off);
            const int   oi = __shfl_xor(bidx[p], off);
            if (ov < best[p] || (ov == best[p] && oi < bidx[p])) {
                best[p] = ov; bidx[p] = oi;
            }
        }
    }
    if (l < 16) {
        #pragma unroll
        for (int p = 0; p < 4; ++p) {
            bestH[h][pg * 64 + p * 16 + col] = best[p];
            bidxH[h][pg * 64 + p * 16 + col] = bidx[p];
        }
    }
    __syncthreads();

    // combine the 2 K-halves: half0 has lower k -> strict < only replaces
    if (tid < PPB) {
        const float b0 = bestH[0][tid];
        const float b1 = bestH[1][tid];
        bfin[tid] = (b1 < b0) ? bidxH[1][tid] : bidxH[0][tid];
    }
    __syncthreads();

    // dense epilogue: q from global, x from LDS z-tile; lane-linear stores
    #pragma unroll
    for (int i = 0; i < (PPB * 16) / BLOCK; ++i) {   // 8 iters
        const int idx = i * BLOCK + tid;
        const int p   = idx >> 4;
        const int j   = idx & 15;
        const float4 q = ef4[bfin[p] * 16 + j];
        const float4 x = zt[p * ZSTR + j];
        float4 o;
        o.x = (q.x + x.x) - x.x;
        o.y = (q.y + x.y) - x.y;
        o.z = (q.z + x.z) - x.z;
        o.w = (q.w + x.w) - x.w;
        of4[(base + p) * 16 + j] = o;
    }
}

extern "C" void kernel_launch(void* const* d_in, const int* in_sizes, int n_in,
                              void* d_out, int out_size, void* d_ws, size_t ws_size,
                              hipStream_t stream) {
    const float* z   = (const float*)d_in[0];
    const float* emb = (const float*)d_in[1];
    float* out = (float*)d_out;

    // ws: e2 f32[512] (2KB) | wsHi short8[4096] (64KB) | wsLo short8[4096] (64KB)
    float*  e2   = (float*)d_ws;
    short8* wsHi = (short8*)((char*)d_ws + 2048);
    short8* wsLo = (short8*)((char*)d_ws + 2048 + 65536);

    prep_emb<<<16, 256, 0, stream>>>(emb, e2, wsHi, wsLo);
    vq_mfma<<<NPTS / PPB, BLOCK, 0, stream>>>(z, emb, e2, wsHi, wsLo, out);
}